// Round 4
// baseline (118.707 us; speedup 1.0000x reference)
//
#include <hip/hip_runtime.h>

// MetaUpSampler via bf16 MFMA — round 11 (= R10 minus the xt round trip).
// R10 result: 118.2us total; top-5 all harness fills (43-44us). Decomposition:
//   fill ~43 + harness tiny-memsets ~35 + prep ~11 + meta ~15-20 + gaps.
//   Controllable remainder = prep + meta + 1 launch gap ~= 25-30us vs ~12 floor.
// R11 fix: drop the NCHW->NHWC pre-transpose (prep) entirely. With 3 output
//   rows per block (R9), direct NCHW staging is only 107 dword loads/lane
//   (R7's failure was 64/lane for 1/3 the output, ~8 in flight). A 2-deep
//   register pipeline keeps ~16 loads in flight; wch-minor XCD mapping makes
//   the 1.67x h-row overlap an own-L2 hit. LDS image is BIT-IDENTICAL to
//   R10's (same f2bf, same cb^(j&7) swizzle) -> MFMA loop/epilogue untouched.
//   Write-side banks: lane=j gives distinct cb^(j&7) per 8-lane phase ✓.
// Workspace: lwb @ 0 (55KB) only; xt eliminated.

#define HH   192
#define WWD  192
#define SS   4
#define OC   3
#define PO   48
#define HID  256
#define W2LD 1728

typedef short  bf16x8 __attribute__((ext_vector_type(8)));
typedef float  f32x4  __attribute__((ext_vector_type(4)));

static __device__ __forceinline__ short f2bf(float f) {
    unsigned u = __float_as_uint(f);
    unsigned r = (u + 0x7fffu + ((u >> 16) & 1u)) >> 16;   // RNE
    return (short)r;
}

static __device__ __forceinline__ void pin(bf16x8& v) {
    asm volatile("" : "+v"(v));    // force VGPR residency; block load sinking
}

// ---------------- Stage A: MLP -> dynamic weights, bf16, [tap][po][c] -------
__global__ __launch_bounds__(256) void lw_kernel(
        const float* __restrict__ W1, const float* __restrict__ b1,
        const float* __restrict__ W2, const float* __restrict__ b2,
        short* __restrict__ lwb) {
    __shared__ float hlds[HID];
    const int b = blockIdx.x;
    const int t = threadIdx.x;
    const int p = b / 7;
    {
        const float pi = (float)(p >> 2) * 0.25f;
        const float pj = (float)(p & 3) * 0.25f;
        const float v = 0.25f * W1[t] + pi * W1[HID + t] + pj * W1[2 * HID + t]
                      + b1[t];
        hlds[t] = v > 0.f ? v : 0.f;
    }
    __syncthreads();
    const int col = (b % 7) * 256 + t;   // 0..1791 (guard at 1728)
    if (col < W2LD) {
        float a = 0.f;
#pragma unroll 32
        for (int hh = 0; hh < HID; ++hh)
            a += hlds[hh] * W2[hh * W2LD + col];   // coalesced 4B + LDS bcast
        const int o = col % 3, kc = col / 3;
        const int tap = kc % 9, c = kc / 9;
        lwb[(tap * PO + p * 3 + o) * 64 + c] = f2bf(a + b2[col]);
    }
}

// ---------------- Stage B: fused MFMA dynamic conv, 3 h-rows per block ------
// Stages directly from NCHW fp32. Chunk ci = r*8+cb (40 total, wave wv takes
// ci = wv, wv+3, ...): lane j loads 8 channels (cc) coalesced (256B/wave per
// instruction), converts, one conflict-free swizzled ds_write_b128.
__global__ __launch_bounds__(192, 3) void meta_up_mfma(
        const float* __restrict__ x, const short* __restrict__ lwb,
        float* __restrict__ out) {
    __shared__ __align__(16) short smem[5 * 66 * 64];   // 42,240 B
    short* xlds = smem;                    // [r][j][c], c in XOR'd 16B blocks
    float* obuf = (float*)smem;            // reused post-MFMA: 36 x 260 floats

    // XCD-contiguous, wch-minor: XCD k gets g in [96k,96k+96) = contiguous
    // (n,hg) band with ALL 3 wch together -> every x row read by ONE XCD,
    // h-overlap (rows shared by hg,hg+1) hits own L2.
    const int g   = (blockIdx.x & 7) * 96 + (blockIdx.x >> 3);
    const int n   = g / 192;
    const int rem = g % 192;
    const int hg  = rem / 3;
    const int wch = rem % 3;
    const int h0  = hg * 3;
    const int w0  = wch * 64;

    const int tid  = threadIdx.x;
    const int lane = tid & 63, wv = tid >> 6;     // wv = po-tile (16 po each)
    const int quad = lane >> 4, l15 = lane & 15;

    // B fragments first (independent of staging; overlap their L2 latency).
    bf16x8 Bb[2][3];
#pragma unroll
    for (int di = 0; di < 3; ++di) {               // phase 0 (dj=0,kc=0)
        Bb[0][di] = *(const bf16x8*)
            &lwb[((di * 3 + 0) * PO + wv * 16 + l15) * 64 + 0 * 32 + quad * 8];
        pin(Bb[0][di]);
    }

    // ---- staging: 2-deep software-pipelined chunk loads --------------------
    {
        const int gc  = w0 - 1 + lane;
        const bool cok = (unsigned)gc < (unsigned)WWD;
        int ci = wv;                                // wv < 3 < 40 always
        float cur[8];
        {
            const int r = ci >> 3, cb = ci & 7;
            const int gr = h0 - 1 + r;
            const bool ok = cok && ((unsigned)gr < (unsigned)HH);
            const float* __restrict__ p = x +
                ((size_t)(n * 64 + cb * 8) * HH + (ok ? gr : 0)) * WWD + (cok ? gc : 0);
#pragma unroll
            for (int cc = 0; cc < 8; ++cc)
                cur[cc] = ok ? p[(size_t)cc * HH * WWD] : 0.f;
        }
#pragma unroll
        for (int k = 0; k < 14; ++k) {
            const int nx = ci + 3;
            const bool more = (nx < 40);
            float nxt[8];
            if (more) {                             // issue BEFORE consuming cur
                const int r = nx >> 3, cb = nx & 7;
                const int gr = h0 - 1 + r;
                const bool ok = cok && ((unsigned)gr < (unsigned)HH);
                const float* __restrict__ p = x +
                    ((size_t)(n * 64 + cb * 8) * HH + (ok ? gr : 0)) * WWD + (cok ? gc : 0);
#pragma unroll
                for (int cc = 0; cc < 8; ++cc)
                    nxt[cc] = ok ? p[(size_t)cc * HH * WWD] : 0.f;
            }
            {
                const int r = ci >> 3, cb = ci & 7;
                bf16x8 pk;
#pragma unroll
                for (int cc = 0; cc < 8; ++cc) pk[cc] = f2bf(cur[cc]);
                *(bf16x8*)&xlds[(r * 66 + lane) * 64 + ((cb ^ (lane & 7)) << 3)] = pk;
            }
            if (!more) break;
#pragma unroll
            for (int cc = 0; cc < 8; ++cc) cur[cc] = nxt[cc];
            ci = nx;
        }
        // tail columns j = 64, 65 (wave wv covers rows r = wv, wv+3)
        if (lane < 16) {
            const int j  = 64 + (lane >> 3);
            const int cb = lane & 7;
            const int gc2 = w0 - 1 + j;
            const bool cok2 = (unsigned)gc2 < (unsigned)WWD;
            for (int r = wv; r < 5; r += 3) {
                const int gr = h0 - 1 + r;
                const bool ok = cok2 && ((unsigned)gr < (unsigned)HH);
                const float* __restrict__ p = x +
                    ((size_t)(n * 64 + cb * 8) * HH + (ok ? gr : 0)) * WWD + (cok2 ? gc2 : 0);
                bf16x8 pk;
#pragma unroll
                for (int cc = 0; cc < 8; ++cc)
                    pk[cc] = f2bf(ok ? p[(size_t)cc * HH * WWD] : 0.f);
                *(bf16x8*)&xlds[(r * 66 + j) * 64 + ((cb ^ (j & 7)) << 3)] = pk;
            }
        }
    }
    __syncthreads();

    // MFMA: 6 (dj,kc) phases x 4 mt x 5 r; A fragment (r,col,kc) reused for
    // up to 3 di (output rows ih = r - di). 120 ds_reads, 216 MFMAs / wave.
    f32x4 acc[3][4];
#pragma unroll
    for (int ih = 0; ih < 3; ++ih)
#pragma unroll
        for (int mt = 0; mt < 4; ++mt) acc[ih][mt] = (f32x4){0.f, 0.f, 0.f, 0.f};

#pragma unroll
    for (int b = 0; b < 6; ++b) {
        const int dj = b >> 1, kc2 = b & 1;
        if (b < 5) {                                 // rolling B prefetch
            const int djn = (b + 1) >> 1, kcn = (b + 1) & 1;
#pragma unroll
            for (int di = 0; di < 3; ++di) {
                Bb[(b + 1) & 1][di] = *(const bf16x8*)
                    &lwb[((di * 3 + djn) * PO + wv * 16 + l15) * 64 + kcn * 32 + quad * 8];
                pin(Bb[(b + 1) & 1][di]);
            }
        }
#pragma unroll
        for (int mt = 0; mt < 4; ++mt) {
            const int col = mt * 16 + l15 + dj;      // 0..65
            const int blk = (kc2 * 4 + quad) ^ (col & 7);
#pragma unroll
            for (int r = 0; r < 5; ++r) {
                bf16x8 a = *(const bf16x8*)&xlds[(r * 66 + col) * 64 + (blk << 3)];
#pragma unroll
                for (int di = 0; di < 3; ++di) {
                    const int ih = r - di;
                    if (ih >= 0 && ih < 3)
                        acc[ih][mt] = __builtin_amdgcn_mfma_f32_16x16x32_bf16(
                            a, Bb[b & 1][di], acc[ih][mt], 0, 0, 0);
                }
            }
        }
    }

    // Epilogue: transpose D through LDS -> full-line coalesced stores (x3 h).
    __syncthreads();                       // all xlds reads complete
    {
        const int po = wv * 16 + l15;
        const int o  = po % 3;
        const int p  = po / 3;
        const int si = p >> 2, sj = p & 3;
        const int osi = o * 4 + si;
#pragma unroll
        for (int ih = 0; ih < 3; ++ih)
#pragma unroll
            for (int mt = 0; mt < 4; ++mt)
#pragma unroll
                for (int r4 = 0; r4 < 4; ++r4) {
                    const int wl = mt * 16 + quad * 4 + r4;
                    obuf[(ih * 12 + osi) * 260 + wl * 4 + sj] = acc[ih][mt][r4];
                }
    }
    __syncthreads();
    {
        const int osi = tid >> 4;          // 0..11
        const int c16 = tid & 15;
        const int o = osi >> 2, si = osi & 3;
#pragma unroll
        for (int ih = 0; ih < 3; ++ih) {
            const int hh = h0 + ih;
            const size_t base =
                ((size_t)(n * OC + o) * (SS * HH) + (size_t)(SS * hh + si)) * (SS * WWD)
                + (size_t)(4 * w0) + c16 * 16;
            const float* __restrict__ src = &obuf[(ih * 12 + osi) * 260 + c16 * 16];
#pragma unroll
            for (int i = 0; i < 4; ++i)    // 64B contiguous per thread
                *(float4*)&out[base + i * 4] = *(const float4*)&src[i * 4];
        }
    }
}

extern "C" void kernel_launch(void* const* d_in, const int* in_sizes, int n_in,
                              void* d_out, int out_size, void* d_ws, size_t ws_size,
                              hipStream_t stream) {
    const float* x  = (const float*)d_in[0];
    const float* W1 = (const float*)d_in[1];
    const float* b1 = (const float*)d_in[2];
    const float* W2 = (const float*)d_in[3];
    const float* b2 = (const float*)d_in[4];
    float* out = (float*)d_out;
    short* lwb = (short*)d_ws;                  // 27,648 bf16 = 55 KB

    lw_kernel<<<112, 256, 0, stream>>>(W1, b1, W2, b2, lwb);
    meta_up_mfma<<<768, 192, 0, stream>>>(x, lwb, out);
}

// Round 5
// 118.573 us; speedup vs baseline: 1.0011x; 1.0011x over previous
//
#include <hip/hip_runtime.h>

// MetaUpSampler via bf16 MFMA — round 12 (= R10 split + 384-thread meta).
// R11 post-mortem: fused NCHW staging = +12.5us vs NHWC (exactly the prep
//   cost) -> fusion null at 118.7. Split + NHWC staging is the structure.
// Decomposition: fixed harness ~82us (fill 43 + memsets/lw/gaps 39);
//   prep ~12us (near its 9us memory floor); meta_R10 ~23us vs ~13-15 floor.
// meta_R10 is latency-bound: 9 waves/CU = 2.25/SIMD; barrier-separated
//   stage->MFMA->epilogue phases serialize with too little TLP to overlap.
// R12 fix: meta = 384 threads / 6 waves: wg (2) splits the 4 m-tiles,
//   wv (3) keeps po-tiles. Per wave: 108 MFMAs, 60 ds_reads, acc[3][2].
//   18 waves/CU = 4.5/SIMD (2x TLP); LDS image/swizzle/B-frags/prep all
//   byte-identical to validated R10. Staging = flat 2640-item loop
//   (7 x 384, 128B-contiguous, tails folded in).
// Workspace: lwb @ 0 (55KB), xt @ +64KB (18.9MB).

#define HH   192
#define WWD  192
#define SS   4
#define OC   3
#define PO   48
#define HID  256
#define W2LD 1728

typedef short  bf16x8 __attribute__((ext_vector_type(8)));
typedef float  f32x4  __attribute__((ext_vector_type(4)));

static __device__ __forceinline__ short f2bf(float f) {
    unsigned u = __float_as_uint(f);
    unsigned r = (u + 0x7fffu + ((u >> 16) & 1u)) >> 16;   // RNE
    return (short)r;
}

static __device__ __forceinline__ void pin(bf16x8& v) {
    asm volatile("" : "+v"(v));    // force VGPR residency; block load sinking
}

// ---------------- Stage A (fused): MLP -> weights  +  x -> NHWC bf16 -------
// Blocks 0..111: lw MLP. Blocks 112..2415: transpose one (n,h,64w) tile of x
// from NCHW f32 to NHWC bf16 via an LDS tile. (Validated R8/R10 kernel.)
__global__ __launch_bounds__(256) void prep_kernel(
        const float* __restrict__ x,
        const float* __restrict__ W1, const float* __restrict__ b1,
        const float* __restrict__ W2, const float* __restrict__ b2,
        short* __restrict__ lwb, short* __restrict__ xt) {
    const int b = blockIdx.x;
    const int t = threadIdx.x;
    if (b < 112) {
        __shared__ float hlds[HID];
        const int p = b / 7;
        {
            const float pi = (float)(p >> 2) * 0.25f;
            const float pj = (float)(p & 3) * 0.25f;
            const float v = 0.25f * W1[t] + pi * W1[HID + t] + pj * W1[2 * HID + t]
                          + b1[t];
            hlds[t] = v > 0.f ? v : 0.f;
        }
        __syncthreads();
        const int col = (b % 7) * 256 + t;   // 0..1791 (guard at 1728)
        if (col < W2LD) {
            float a = 0.f;
#pragma unroll 32
            for (int hh = 0; hh < HID; ++hh)
                a += hlds[hh] * W2[hh * W2LD + col];   // coalesced 4B + LDS bcast
            const int o = col % 3, kc = col / 3;
            const int tap = kc % 9, c = kc / 9;
            lwb[(tap * PO + p * 3 + o) * 64 + c] = f2bf(a + b2[col]);
        }
    } else {
        __shared__ short tl[64][72];         // [w][c], +8 pad vs bank stride
        const int bb = b - 112;
        const int wt = bb % 3;
        const int h  = (bb / 3) % HH;
        const int n  = bb / (3 * HH);
        const int w0 = wt * 64;
        // read: 1024 float4s; consecutive threads -> consecutive 16B in a row
#pragma unroll
        for (int i = 0; i < 4; ++i) {
            const int idx = i * 256 + t;     // 0..1023
            const int c   = idx >> 4;        // channel 0..63
            const int j4  = idx & 15;        // float4 within 64 w
            const float4 v = *(const float4*)
                &x[(((size_t)(n * 64 + c)) * HH + h) * WWD + w0 + j4 * 4];
            tl[j4 * 4 + 0][c] = f2bf(v.x);
            tl[j4 * 4 + 1][c] = f2bf(v.y);
            tl[j4 * 4 + 2][c] = f2bf(v.z);
            tl[j4 * 4 + 3][c] = f2bf(v.w);
        }
        __syncthreads();
        // write: 32B/thread, 8KB fully contiguous per block
        const int w  = t >> 2;
        const int c0 = (t & 3) * 16;
        short* dst = &xt[(((size_t)n * HH + h) * WWD + w0 + w) * 64 + c0];
        *(bf16x8*)&dst[0] = *(const bf16x8*)&tl[w][c0];
        *(bf16x8*)&dst[8] = *(const bf16x8*)&tl[w][c0 + 8];
    }
}

// ---------------- Stage B: MFMA dynamic conv, 3 h-rows, 6 waves ------------
// wave = (wg, wv): wv = po-tile (16 po), wg = m-tile half (mt = wg*2 + mtl).
__global__ __launch_bounds__(384) void meta_up_mfma(
        const short* __restrict__ xt, const short* __restrict__ lwb,
        float* __restrict__ out) {
    __shared__ __align__(16) short smem[5 * 66 * 64];   // 42,240 B
    short* xlds = smem;                    // [r][j][c], c in XOR'd 16B blocks
    float* obuf = (float*)smem;            // reused post-MFMA: 36 x 260 floats

    // XCD-contiguous mapping (validated R10): 768 = 8 XCDs x 96 contiguous.
    const int g   = (blockIdx.x & 7) * 96 + (blockIdx.x >> 3);
    const int n   = g / 192;
    const int rem = g % 192;
    const int wch = rem / 64;
    const int hg  = rem % 64;
    const int h0  = hg * 3;
    const int w0  = wch * 64;

    const int tid  = threadIdx.x;
    const int lane = tid & 63;
    const int wv   = (tid >> 6) % 3;              // po-tile
    const int wg   = tid >> 7 >= 1 ? (tid >= 256 ? 1 : (tid >= 192 ? 1 : 0)) : 0;
    // waves 0,1,2 -> wg 0; waves 3,4,5 -> wg 1  (tid/64: 0..5)
    const int wgq  = (tid >> 6) / 3;
    const int quad = lane >> 4, l15 = lane & 15;

    // B fragments first (independent of staging; overlap their L2 latency).
    bf16x8 Bb[2][3];
#pragma unroll
    for (int di = 0; di < 3; ++di) {               // phase 0 (dj=0,kc=0)
        Bb[0][di] = *(const bf16x8*)
            &lwb[((di * 3 + 0) * PO + wv * 16 + l15) * 64 + 0 * 32 + quad * 8];
        pin(Bb[0][di]);
    }

    // Stage 5 rows x 66 cols x 8 cb = 2640 16B-items, flat over 384 threads.
    {
        const bf16x8 z = {0, 0, 0, 0, 0, 0, 0, 0};
#pragma unroll
        for (int k = 0; k < 7; ++k) {
            const int item = k * 384 + tid;
            if (item < 2640) {
                const int r   = item / 528;          // 0..4
                const int rm  = item - r * 528;
                const int j   = rm >> 3;             // 0..65
                const int cb  = rm & 7;
                const int gr  = h0 - 1 + r;
                const int gc  = w0 - 1 + j;
                const bool ok = ((unsigned)gr < (unsigned)HH) &&
                                ((unsigned)gc < (unsigned)WWD);
                const bf16x8 v = ok ? *(const bf16x8*)
                    &xt[((size_t)(n * HH + gr) * WWD + gc) * 64 + cb * 8] : z;
                *(bf16x8*)&xlds[(r * 66 + j) * 64 + ((cb ^ (j & 7)) << 3)] = v;
            }
        }
    }
    __syncthreads();

    // MFMA: 6 (dj,kc) phases x 2 mtl x 5 r; A fragment reused over up to
    // 3 di (output rows ih = r - di). 60 ds_reads, 108 MFMAs per wave.
    f32x4 acc[3][2];
#pragma unroll
    for (int ih = 0; ih < 3; ++ih)
#pragma unroll
        for (int mtl = 0; mtl < 2; ++mtl) acc[ih][mtl] = (f32x4){0.f, 0.f, 0.f, 0.f};

#pragma unroll
    for (int b = 0; b < 6; ++b) {
        const int dj = b >> 1, kc2 = b & 1;
        if (b < 5) {                                 // rolling B prefetch
            const int djn = (b + 1) >> 1, kcn = (b + 1) & 1;
#pragma unroll
            for (int di = 0; di < 3; ++di) {
                Bb[(b + 1) & 1][di] = *(const bf16x8*)
                    &lwb[((di * 3 + djn) * PO + wv * 16 + l15) * 64 + kcn * 32 + quad * 8];
                pin(Bb[(b + 1) & 1][di]);
            }
        }
#pragma unroll
        for (int mtl = 0; mtl < 2; ++mtl) {
            const int mt  = wgq * 2 + mtl;
            const int col = mt * 16 + l15 + dj;      // 0..65
            const int blk = (kc2 * 4 + quad) ^ (col & 7);
#pragma unroll
            for (int r = 0; r < 5; ++r) {
                bf16x8 a = *(const bf16x8*)&xlds[(r * 66 + col) * 64 + (blk << 3)];
#pragma unroll
                for (int di = 0; di < 3; ++di) {
                    const int ih = r - di;
                    if (ih >= 0 && ih < 3)
                        acc[ih][mtl] = __builtin_amdgcn_mfma_f32_16x16x32_bf16(
                            a, Bb[b & 1][di], acc[ih][mtl], 0, 0, 0);
                }
            }
        }
    }

    // Epilogue: transpose D through LDS -> full-line coalesced stores (x3 h).
    __syncthreads();                       // all xlds reads complete
    {
        const int po = wv * 16 + l15;
        const int o  = po % 3;
        const int p  = po / 3;
        const int si = p >> 2, sj = p & 3;
        const int osi = o * 4 + si;
#pragma unroll
        for (int ih = 0; ih < 3; ++ih)
#pragma unroll
            for (int mtl = 0; mtl < 2; ++mtl) {
                const int mt = wgq * 2 + mtl;
#pragma unroll
                for (int r4 = 0; r4 < 4; ++r4) {
                    const int wl = mt * 16 + quad * 4 + r4;
                    obuf[(ih * 12 + osi) * 260 + wl * 4 + sj] = acc[ih][mtl][r4];
                }
            }
    }
    __syncthreads();
    {
        // 2304 float4s = 3 ih x (2 x 384): idx = h2*384+tid -> osi, c4.
#pragma unroll
        for (int ih = 0; ih < 3; ++ih)
#pragma unroll
            for (int h2 = 0; h2 < 2; ++h2) {
                const int idx = h2 * 384 + tid;      // 0..767
                const int osi = idx >> 6;            // 0..11
                const int c4  = idx & 63;
                const int o = osi >> 2, si = osi & 3;
                const int hh = h0 + ih;
                const size_t base =
                    ((size_t)(n * OC + o) * (SS * HH) + (size_t)(SS * hh + si))
                        * (SS * WWD) + (size_t)(4 * w0) + c4 * 4;
                *(float4*)&out[base] =
                    *(const float4*)&obuf[(ih * 12 + osi) * 260 + c4 * 4];
            }
    }
}

extern "C" void kernel_launch(void* const* d_in, const int* in_sizes, int n_in,
                              void* d_out, int out_size, void* d_ws, size_t ws_size,
                              hipStream_t stream) {
    const float* x  = (const float*)d_in[0];
    const float* W1 = (const float*)d_in[1];
    const float* b1 = (const float*)d_in[2];
    const float* W2 = (const float*)d_in[3];
    const float* b2 = (const float*)d_in[4];
    float* out = (float*)d_out;
    short* lwb = (short*)d_ws;                  // 27,648 bf16 = 55 KB
    short* xt  = (short*)d_ws + 32768;          // NHWC bf16 x, 18.9 MB

    prep_kernel<<<112 + 4 * HH * 3, 256, 0, stream>>>(x, W1, b1, W2, b2, lwb, xt);
    meta_up_mfma<<<768, 384, 0, stream>>>(xt, lwb, out);
}